// Round 3
// baseline (210.324 us; speedup 1.0000x reference)
//
#include <hip/hip_runtime.h>
#include <math.h>

// Gate / MoE router: logits = x @ W^T (T=16384, D=2048, E=8), softmax, top-2,
// renormalize. out = [T*2] weights (fp32) ++ [T*2] indices (as fp32).
//
// Renormalized top-2 softmax: w1 = 1/(1+exp(l2-l1)), w2 = 1-w1 (Z cancels).
//
// R3 vs R2: 8 tokens/wave (halves W re-read traffic 256->128 MiB, vmem mix
// 1:1 x:W). NV=64 partials -> 63-shuffle value-splitting butterfly; after it,
// lane L holds the fully-reduced value of index L (lane bit b <-> value bit b
// at each exchange step), so the LDS bounce is one store per lane, no dups.

constexpr int D = 2048;
constexpr int E = 8;
constexpr int NT = 16384;
constexpr int T_PER_WAVE = 8;       // tokens per wave
constexpr int WAVES_PER_BLOCK = 4;  // 256-thread blocks
constexpr int BLOCK = WAVES_PER_BLOCK * 64;
constexpr int CHUNK = 64 * 4;       // floats per wave per K-iteration
constexpr int NV = T_PER_WAVE * E;  // 64 partial values per lane

typedef float fvec4 __attribute__((ext_vector_type(4)));

__global__ __launch_bounds__(BLOCK, 2) void gate_kernel(
    const float* __restrict__ x, const float* __restrict__ W,
    float* __restrict__ out) {
  const int lane = threadIdx.x & 63;
  const int wslot = threadIdx.x >> 6;
  const int wave = blockIdx.x * WAVES_PER_BLOCK + wslot;
  const int t0 = wave * T_PER_WAVE;  // first token this wave owns

  float v[NV];  // v[t*E+e]
#pragma unroll
  for (int i = 0; i < NV; i++) v[i] = 0.f;

  // K loop: lane l covers k = c*256 + l*4 .. +3 (fully coalesced 1KiB/inst)
  for (int c = 0; c < D / CHUNK; c++) {
    const int k = c * CHUNK + lane * 4;
    fvec4 xv[T_PER_WAVE];
#pragma unroll
    for (int t = 0; t < T_PER_WAVE; t++)
      xv[t] = __builtin_nontemporal_load(
          (const fvec4*)(x + (size_t)(t0 + t) * D + k));
#pragma unroll
    for (int e = 0; e < E; e++) {
      const fvec4 wv = *(const fvec4*)(W + (size_t)e * D + k);
#pragma unroll
      for (int t = 0; t < T_PER_WAVE; t++) {
        v[t * E + e] += xv[t].x * wv.x;
        v[t * E + e] += xv[t].y * wv.y;
        v[t * E + e] += xv[t].z * wv.z;
        v[t * E + e] += xv[t].w * wv.w;
      }
    }
  }

  // Value-splitting exchange butterfly: 32+16+8+4+2+1 = 63 shuffles.
  // Invariant: at step with mask o, value-index bit log2(o) pairs with lane
  // bit log2(o). Final: lane L holds the wave-wide sum of value index L.
  int n = NV / 2;
#pragma unroll
  for (int o = 32; o >= 1; o >>= 1) {
    const bool upper = (lane & o) != 0;
#pragma unroll
    for (int i = 0; i < 32; i++) {
      if (i < n) {
        const float send = upper ? v[i] : v[i + n];
        const float keep = upper ? v[i + n] : v[i];
        v[i] = keep + __shfl_xor(send, o, 64);
      }
    }
    n >>= 1;
  }

  // One store per lane: reduced logit for token (lane>>3), expert (lane&7).
  __shared__ float red[WAVES_PER_BLOCK][NV];
  red[wslot][lane] = v[0];
  __syncthreads();

  if (lane < T_PER_WAVE) {
    const int t = lane;
    float l[E];
#pragma unroll
    for (int e = 0; e < E; e++) l[e] = red[wslot][t * E + e];
    // top-1 (strict > keeps lowest index on ties, matching lax.top_k)
    float m1 = l[0];
    int i1 = 0;
#pragma unroll
    for (int e = 1; e < E; e++)
      if (l[e] > m1) { m1 = l[e]; i1 = e; }
    float m2 = -INFINITY;
    int i2 = 0;
#pragma unroll
    for (int e = 0; e < E; e++)
      if (e != i1 && l[e] > m2) { m2 = l[e]; i2 = e; }
    const float s = __expf(m2 - m1);  // <= 1
    const float w1 = 1.f / (1.f + s);
    // 8 lanes -> 64B contiguous per output array
    *(float2*)(out + 2 * (size_t)(t0 + t)) = make_float2(w1, 1.f - w1);
    *(float2*)(out + 2 * (size_t)NT + 2 * (size_t)(t0 + t)) =
        make_float2((float)i1, (float)i2);
  }
}

extern "C" void kernel_launch(void* const* d_in, const int* in_sizes, int n_in,
                              void* d_out, int out_size, void* d_ws,
                              size_t ws_size, hipStream_t stream) {
  const float* x = (const float*)d_in[0];
  const float* W = (const float*)d_in[1];
  float* out = (float*)d_out;
  const int blocks = NT / (T_PER_WAVE * WAVES_PER_BLOCK);  // 512
  gate_kernel<<<blocks, BLOCK, 0, stream>>>(x, W, out);
}

// Round 4
// 192.619 us; speedup vs baseline: 1.0919x; 1.0919x over previous
//
#include <hip/hip_runtime.h>

// Gate / MoE router: logits = x @ W^T, softmax over E=8, top-2, renormalize.
// x: [T=16384, D=2048] fp32, W: [E=8, D=2048] fp32.
// out: [T*2] routing weights (fp32) followed by [T*2] expert indices (as fp32).
//
// Renormalized top-2 softmax simplifies: w1 = 1/(1+exp(l2-l1)), w2 = 1-w1
// (full softmax denominator cancels), so no full softmax needed.
//
// R4 = exact re-submission of R1 (best measured: 194.3 us) as a noise
// calibration. R2 (+NT loads, split butterfly: 205.4) and R3 (+8 tok/wave:
// 210.3) both drifted upward; this run disambiguates real-regression vs
// harness noise (~180 us of the dur_us is poison-fill + restore traffic;
// kernel itself is <78 us, never in rocprof top-5).

constexpr int D = 2048;
constexpr int E = 8;
constexpr int NT = 16384;
constexpr int T_PER_WAVE = 4;       // tokens per wave
constexpr int WAVES_PER_BLOCK = 4;  // 256-thread blocks
constexpr int BLOCK = WAVES_PER_BLOCK * 64;
constexpr int CHUNK = 64 * 4;       // floats per wave per K-iteration

__global__ __launch_bounds__(BLOCK) void gate_kernel(
    const float* __restrict__ x, const float* __restrict__ W,
    float* __restrict__ out) {
  const int lane = threadIdx.x & 63;
  const int wave = blockIdx.x * WAVES_PER_BLOCK + (threadIdx.x >> 6);
  const int t0 = wave * T_PER_WAVE;  // first token this wave owns

  float acc[T_PER_WAVE][E];
#pragma unroll
  for (int t = 0; t < T_PER_WAVE; t++)
#pragma unroll
    for (int e = 0; e < E; e++) acc[t][e] = 0.f;

  // K loop: per chunk, lane l covers k = c*256 + l*4 .. +3 (coalesced float4)
  for (int c = 0; c < D / CHUNK; c++) {
    const int k = c * CHUNK + lane * 4;
    float4 xv[T_PER_WAVE];
#pragma unroll
    for (int t = 0; t < T_PER_WAVE; t++)
      xv[t] = *(const float4*)(x + (size_t)(t0 + t) * D + k);
#pragma unroll
    for (int e = 0; e < E; e++) {
      const float4 wv = *(const float4*)(W + (size_t)e * D + k);
#pragma unroll
      for (int t = 0; t < T_PER_WAVE; t++) {
        acc[t][e] += xv[t].x * wv.x;
        acc[t][e] += xv[t].y * wv.y;
        acc[t][e] += xv[t].z * wv.z;
        acc[t][e] += xv[t].w * wv.w;
      }
    }
  }

  // Butterfly reduce each of the 32 partials across the 64-lane wave.
#pragma unroll
  for (int t = 0; t < T_PER_WAVE; t++)
#pragma unroll
    for (int e = 0; e < E; e++) {
      float v = acc[t][e];
#pragma unroll
      for (int off = 32; off; off >>= 1) v += __shfl_xor(v, off, 64);
      acc[t][e] = v;
    }

  if (lane == 0) {
    float w1v[T_PER_WAVE], w2v[T_PER_WAVE];
    float i1v[T_PER_WAVE], i2v[T_PER_WAVE];
#pragma unroll
    for (int t = 0; t < T_PER_WAVE; t++) {
      // top-1 (strict > keeps lowest index on ties, matching lax.top_k)
      float m1 = acc[t][0];
      int i1 = 0;
#pragma unroll
      for (int e = 1; e < E; e++)
        if (acc[t][e] > m1) { m1 = acc[t][e]; i1 = e; }
      // top-2 among the rest
      float m2 = -INFINITY;
      int i2 = 0;
#pragma unroll
      for (int e = 0; e < E; e++)
        if (e != i1 && acc[t][e] > m2) { m2 = acc[t][e]; i2 = e; }
      const float s = __expf(m2 - m1);   // exp(l2-l1) <= 1
      const float w1 = 1.f / (1.f + s);
      w1v[t] = w1;
      w2v[t] = 1.f - w1;
      i1v[t] = (float)i1;
      i2v[t] = (float)i2;
    }
    // 4 consecutive tokens -> 8 contiguous floats per output array
    float4* ow = (float4*)(out + 2 * (size_t)t0);
    ow[0] = make_float4(w1v[0], w2v[0], w1v[1], w2v[1]);
    ow[1] = make_float4(w1v[2], w2v[2], w1v[3], w2v[3]);
    float4* oi = (float4*)(out + 2 * (size_t)NT + 2 * (size_t)t0);
    oi[0] = make_float4(i1v[0], i2v[0], i1v[1], i2v[1]);
    oi[1] = make_float4(i1v[2], i2v[2], i1v[3], i2v[3]);
  }
}

extern "C" void kernel_launch(void* const* d_in, const int* in_sizes, int n_in,
                              void* d_out, int out_size, void* d_ws,
                              size_t ws_size, hipStream_t stream) {
  const float* x = (const float*)d_in[0];
  const float* W = (const float*)d_in[1];
  float* out = (float*)d_out;
  const int blocks = NT / (T_PER_WAVE * WAVES_PER_BLOCK);  // 1024
  gate_kernel<<<blocks, BLOCK, 0, stream>>>(x, W, out);
}